// Round 15
// baseline (152.017 us; speedup 1.0000x reference)
//
#include <hip/hip_runtime.h>

// Chamfer distance — exact, pruned by x-binning.
// R15-R17: adaptive outward scans pinned ~48us (serial per-tile chain).
// R18: fixed windows + parallel chunks: chain gone, but (a) slab-max over
// 64 preds -> loose windows (347M pairs), (b) tiny blocks = 900cy VALU in
// ~3000cy lifetime at 3 blocks/CU -> 70% idle.
// R19: SLABP=32 (tighter bmax + less x-spread); block = slab looping its
// PRECOMPUTED window with R10-style reg->LDS double-buffer (stage k+1
// issued before compute k, 1 barrier/chunk, no dependencies); no atomics
// (slab owns preds -> direct store), no wsmin memset. Exact: excluded
// targets have (dx)^2 > bmax >= NN^2 for all slab preds (+-1 bin margin).
// Predict: slab kernel 12-18us, bench 48-62us, absmax 0.
//
// Carried: pk_fma = 2x scalar cost (packing useless for fp32 throughput);
// launch_bounds arg2 = min BLOCKS/CU, VGPR cap = 2048/(arg2 x waves);
// brute floor 46.3us dispatch.

#define NBINS 256
#define XLO -6.0f
#define XHI 6.0f

#define SLABP 32    // preds per slab
#define CHUNK 512   // targets per staged chunk
#define LROW 65     // 64 + 1 float4 pad -> rows at banks {0,4,..,28}
#define UBN 64      // ub scan: +-UBN positions around pred's bin start

// bin sort
#define BST 1024

// brute-force fallback params (R11, unchanged)
#define THREADS 512
#define P 8
#define G 128
#define TILE 32
#define LSTRIDE (TILE + 1)
#define TSPLIT 2
#define BUFSZ (32 * LSTRIDE)

typedef float float2_t __attribute__((ext_vector_type(2)));
typedef float float4_t __attribute__((ext_vector_type(4)));

// ---------- pass 1: counting sort by x-bin, emit float4 {x,y,z,|q|^2} ----
__global__ __launch_bounds__(BST) void bin_sort_kernel(
    const float* __restrict__ pred, const float* __restrict__ target,
    float4_t* __restrict__ sorted, int* __restrict__ binBase, int M) {
  int bs = blockIdx.x;  // b*2 + side
  int b = bs >> 1, side = bs & 1;
  const float* src = (side ? target : pred) + (size_t)b * M * 3;
  float4_t* out = sorted + (size_t)bs * M;
  int* bases = binBase + bs * (NBINS + 1);

  __shared__ int cnt[NBINS];
  __shared__ int scan[NBINS];
  __shared__ int cur[NBINS];
  int t = threadIdx.x;
  for (int i = t; i < NBINS; i += BST) cnt[i] = 0;
  __syncthreads();
  const float invW = (float)NBINS / (XHI - XLO);
  for (int i = t; i < M; i += BST) {
    float x = src[i * 3];
    int bin = (int)((x - XLO) * invW);
    bin = bin < 0 ? 0 : (bin > NBINS - 1 ? NBINS - 1 : bin);
    atomicAdd(&cnt[bin], 1);
  }
  __syncthreads();
  if (t < NBINS) scan[t] = cnt[t];
  __syncthreads();
  for (int off = 1; off < NBINS; off <<= 1) {
    int v = 0;
    if (t < NBINS && t >= off) v = scan[t - off];
    __syncthreads();
    if (t < NBINS) scan[t] += v;
    __syncthreads();
  }
  if (t < NBINS) {
    int excl = scan[t] - cnt[t];
    bases[t] = excl;
    cur[t] = excl;
  }
  if (t == 0) bases[NBINS] = M;
  __syncthreads();
  for (int i = t; i < M; i += BST) {
    float x = src[i * 3], y = src[i * 3 + 1], z = src[i * 3 + 2];
    int bin = (int)((x - XLO) * invW);
    bin = bin < 0 ? 0 : (bin > NBINS - 1 ? NBINS - 1 : bin);
    int pos = atomicAdd(&cur[bin], 1);
    out[pos] = (float4_t){x, y, z, x * x + y * y + z * z};
  }
}

// ---------- pass 2: per-slab window from per-pred NN upper bounds -------
// 64-thread block = 2 slabs of 32 preds (width-32 shuffle reduces).
__global__ __launch_bounds__(64) void bound_kernel(
    const float4_t* __restrict__ sorted, const int* __restrict__ binBase,
    int* __restrict__ hdr, int M) {
  int t = threadIdx.x;
  int s = blockIdx.x * 2 + (t >> 5);  // slab id
  int l = t & 31;                     // pred lane within slab
  int spd = M / SLABP;                // slabs per side (256)
  int bs = s / spd;
  int pblk = s % spd;
  const float4_t* src = sorted + (size_t)bs * M;
  const float4_t* ref = sorted + (size_t)(bs ^ 1) * M;
  const int* rbase = binBase + (bs ^ 1) * (NBINS + 1);

  int pbase = pblk * SLABP;
  float4_t p = src[pbase + l];
  float ax = -2.f * p.x, ay = -2.f * p.y, az = -2.f * p.z;

  const float W = (XHI - XLO) / (float)NBINS;
  const float invW = 1.0f / W;
  int bin = (int)((p.x - XLO) * invW);
  bin = bin < 0 ? 0 : (bin > NBINS - 1 ? NBINS - 1 : bin);
  int pos0 = rbase[bin];
  int lo = pos0 - UBN; lo = lo < 0 ? 0 : lo;
  int hi = pos0 + UBN; hi = hi > M ? M : hi;
  float ub = 3.0e38f;  // min over a SUBSET of targets -> valid upper bound
  for (int j = lo; j < hi; ++j) {
    float4_t q = ref[j];
    float d = fmaf(ax, q.x, fmaf(ay, q.y, fmaf(az, q.z, q.w)));
    ub = fminf(ub, d);
  }
  ub += p.w;  // true NN dist^2 <= ub  (window non-empty: contains ub target)

  float bmax = ub, xmn = p.x, xmx = p.x;
#pragma unroll
  for (int off = 1; off < 32; off <<= 1) {  // width-32: within slab half
    bmax = fmaxf(bmax, __shfl_xor(bmax, off, 32));
    xmn = fminf(xmn, __shfl_xor(xmn, off, 32));
    xmx = fmaxf(xmx, __shfl_xor(xmx, off, 32));
  }
  if (l == 0) {
    float r = sqrtf(bmax) * 1.0005f;  // fp safety pad (plus +-1 bin margin)
    int lb = (int)floorf((xmn - r - XLO) * invW) - 1;
    lb = lb < 0 ? 0 : (lb > NBINS - 1 ? NBINS - 1 : lb);
    int rb = (int)floorf((xmx + r - XLO) * invW) + 1;
    rb = rb < 0 ? 0 : (rb > NBINS - 1 ? NBINS - 1 : rb);
    int Lpos = rbase[lb];
    int Rpos = rbase[rb + 1];
    int nch = (Rpos - Lpos + CHUNK - 1) / CHUNK;  // <= M/CHUNK = 16
    hdr[s * 4 + 0] = Lpos;
    hdr[s * 4 + 1] = Rpos;
    hdr[s * 4 + 2] = nch;
    hdr[s * 4 + 3] = 0;
  }
}

// ---------- pass 3: slab scan over fixed window, double-buffered --------
__global__ __launch_bounds__(256, 6) void slab_kernel(
    const float4_t* __restrict__ sorted, const int* __restrict__ hdr,
    float* __restrict__ wsmin, int M) {
  int s = blockIdx.x;
  int spd = M / SLABP;
  int bs = s / spd;
  int pblk = s % spd;
  const float4_t* src = sorted + (size_t)bs * M;
  const float4_t* ref = sorted + (size_t)(bs ^ 1) * M;
  int pbase = pblk * SLABP;

  int Lpos = hdr[s * 4 + 0];
  int Rpos = hdr[s * 4 + 1];
  int nch = hdr[s * 4 + 2];
  nch = nch > 16 ? 16 : nch;  // defensive (never binding if correct)

  __shared__ float4_t buf[2][8 * LROW];  // 16.6 KB double buffer

  int t = threadIdx.x;
  int c = t >> 3;  // cluster 0..31 = pred index
  int r = t & 7;   // row 0..7: targets [r*64, r*64+64) of the chunk

  float4_t p = src[pbase + c];
  float ax = -2.f * p.x, ay = -2.f * p.y, az = -2.f * p.z, cm = p.w;
  float mn = 3.0e38f;

  // stage addressing: thread owns entries t and t+256 of each 512-chunk
  const int i0 = t, i1 = t + 256;
  float4_t s0, s1;
#define LDCH(k_)                                                      \
  {                                                                   \
    int start_ = Lpos + (k_)*CHUNK;                                   \
    int fill_ = Rpos - start_;                                        \
    s0 = (float4_t){0.f, 0.f, 0.f, 3.0e38f};                          \
    s1 = (float4_t){0.f, 0.f, 0.f, 3.0e38f};                          \
    if (i0 < fill_) s0 = ref[start_ + i0];                            \
    if (i1 < fill_) s1 = ref[start_ + i1];                            \
  }
#define WRCH(bb_)                                                     \
  {                                                                   \
    buf[bb_][(i0 >> 6) * LROW + (i0 & 63)] = s0;                      \
    buf[bb_][(i1 >> 6) * LROW + (i1 & 63)] = s1;                      \
  }

  LDCH(0) WRCH(0)
  __syncthreads();
  int cur = 0;
  for (int k = 0; k < nch; ++k) {
    if (k + 1 < nch) LDCH(k + 1)  // in flight under compute
    const float4_t* tp = &buf[cur][r * LROW];
#pragma unroll 2
    for (int j = 0; j < 64; j += 4) {
      float4_t q0 = tp[j + 0];  // 8 rows/wave at banks {0,4,..,28}
      float4_t q1 = tp[j + 1];
      float4_t q2 = tp[j + 2];
      float4_t q3 = tp[j + 3];
      float d0 = fmaf(ax, q0.x, fmaf(ay, q0.y, fmaf(az, q0.z, q0.w)));
      float d1 = fmaf(ax, q1.x, fmaf(ay, q1.y, fmaf(az, q1.z, q1.w)));
      float d2 = fmaf(ax, q2.x, fmaf(ay, q2.y, fmaf(az, q2.z, q2.w)));
      float d3 = fmaf(ax, q3.x, fmaf(ay, q3.y, fmaf(az, q3.z, q3.w)));
      mn = fminf(fminf(mn, d0), d1);  // v_min3
      mn = fminf(fminf(mn, d2), d3);
    }
    if (k + 1 < nch) WRCH(cur ^ 1)
    __syncthreads();
    cur ^= 1;
  }
#undef LDCH
#undef WRCH

  // cluster reduce (xor 1,2,4 toggles only r bits) and direct store
  mn = fminf(mn, __shfl_xor(mn, 1, 64));
  mn = fminf(mn, __shfl_xor(mn, 2, 64));
  mn = fminf(mn, __shfl_xor(mn, 4, 64));
  if (r == 0) wsmin[(size_t)bs * M + pbase + c] = mn + cm;
}

// ---------- pass 4: sum wsmin -------------------------------------------
__global__ __launch_bounds__(256) void chamfer_reduce_kernel(
    const float* __restrict__ wsmin, float* __restrict__ out, int npts,
    float scale) {
  int tid = blockIdx.x * blockDim.x + threadIdx.x;
  int stride = gridDim.x * blockDim.x;
  double acc = 0.0;
  for (int p = tid; p < npts; p += stride) acc += (double)wsmin[p];
  for (int off = 32; off > 0; off >>= 1) acc += __shfl_down(acc, off, 64);
  __shared__ double wsum[256 / 64];
  int t = threadIdx.x;
  if ((t & 63) == 0) wsum[t >> 6] = acc;
  __syncthreads();
  if (t == 0) {
    double s = 0.0;
#pragma unroll
    for (int w = 0; w < 256 / 64; ++w) s += wsum[w];
    atomicAdd(out, (float)(s * (double)scale));
  }
}

// =================== fallback: R11 brute force (512KB ws) ===============
__global__ __launch_bounds__(THREADS, 2) void chamfer_brute_kernel(
    const float* __restrict__ pred, const float* __restrict__ target,
    float* __restrict__ wsmin, int M) {
  const int blocksPerDir = M / G;  // 64
  int bid = blockIdx.x;
  int pblk = bid % blocksPerDir;
  int rest = bid / blocksPerDir;
  int ts = rest % TSPLIT;
  int bd = rest / TSPLIT;
  int dir = bd & 1;
  int b = bd >> 1;
  const float* src = (dir ? target : pred) + (size_t)b * M * 3;
  const float* ref = (dir ? pred : target) + (size_t)b * M * 3;

  __shared__ float4_t lds[2 * BUFSZ];

  int t = threadIdx.x;
  int g = t >> 4;
  int l = t & 15;

  float ax[P], ay[P], az[P];
  int pbase = pblk * G;
#pragma unroll
  for (int i = 0; i < P; ++i) {
    int p = pbase + l + 16 * i;
    float x = src[p * 3 + 0], y = src[p * 3 + 1], z = src[p * 3 + 2];
    ax[i] = -2.f * x;
    ay[i] = -2.f * y;
    az[i] = -2.f * z;
  }
  float mn[P];
#pragma unroll
  for (int i = 0; i < P; ++i) mn[i] = 3.0e38f;

  const int spanLen = M / TSPLIT;
  const int tbase = ts * spanLen;
  const int sliceLen = spanLen / 32;   // 128
  const int ntiles = sliceLen / TILE;  // 4

  const int sidx = 2 * t;
  const int ss = sidx >> 5;
  const int sjj = sidx & (TILE - 1);
  const int nb = tbase + ss * sliceLen + sjj;
  float rx0, ry0, rz0, rx1, ry1, rz1;

  {
    int n = nb;
    rx0 = ref[n * 3 + 0]; ry0 = ref[n * 3 + 1]; rz0 = ref[n * 3 + 2];
    rx1 = ref[n * 3 + 3]; ry1 = ref[n * 3 + 4]; rz1 = ref[n * 3 + 5];
    float4_t* dst = lds + ss * LSTRIDE + sjj;
    dst[0] = (float4_t){rx0, ry0, rz0, rx0 * rx0 + ry0 * ry0 + rz0 * rz0};
    dst[1] = (float4_t){rx1, ry1, rz1, rx1 * rx1 + ry1 * ry1 + rz1 * rz1};
  }
  __syncthreads();

  int cur = 0;
  for (int k = 0; k < ntiles; ++k) {
    if (k + 1 < ntiles) {
      int n = nb + (k + 1) * TILE;
      rx0 = ref[n * 3 + 0]; ry0 = ref[n * 3 + 1]; rz0 = ref[n * 3 + 2];
      rx1 = ref[n * 3 + 3]; ry1 = ref[n * 3 + 4]; rz1 = ref[n * 3 + 5];
    }
    const float4_t* tp = lds + cur * BUFSZ + g * LSTRIDE;
#pragma unroll 2
    for (int j = 0; j < TILE; j += 4) {
      float4_t q0 = tp[j + 0];
      float4_t q1 = tp[j + 1];
      float4_t q2 = tp[j + 2];
      float4_t q3 = tp[j + 3];
#pragma unroll
      for (int i = 0; i < P; ++i) {
        float d0 = fmaf(ax[i], q0.x, fmaf(ay[i], q0.y, fmaf(az[i], q0.z, q0.w)));
        float d1 = fmaf(ax[i], q1.x, fmaf(ay[i], q1.y, fmaf(az[i], q1.z, q1.w)));
        float d2 = fmaf(ax[i], q2.x, fmaf(ay[i], q2.y, fmaf(az[i], q2.z, q2.w)));
        float d3 = fmaf(ax[i], q3.x, fmaf(ay[i], q3.y, fmaf(az[i], q3.z, q3.w)));
        mn[i] = fminf(fminf(mn[i], d0), d1);
        mn[i] = fminf(fminf(mn[i], d2), d3);
      }
    }
    if (k + 1 < ntiles) {
      float4_t* dst = lds + (cur ^ 1) * BUFSZ + ss * LSTRIDE + sjj;
      dst[0] = (float4_t){rx0, ry0, rz0, rx0 * rx0 + ry0 * ry0 + rz0 * rz0};
      dst[1] = (float4_t){rx1, ry1, rz1, rx1 * rx1 + ry1 * ry1 + rz1 * rz1};
    }
    __syncthreads();
    cur ^= 1;
  }

  float* lmin = (float*)lds;
#pragma unroll
  for (int i = 0; i < P; ++i) lmin[g * G + (l + 16 * i)] = mn[i];
  __syncthreads();
  if (t < G) {
    float m = 3.0e38f;
#pragma unroll
    for (int s = 0; s < 32; ++s) m = fminf(m, lmin[s * G + t]);
    int p = pbase + t;
    float x = src[p * 3 + 0], y = src[p * 3 + 1], z = src[p * 3 + 2];
    int pid = (b * 2 + dir) * M + p;
    wsmin[(size_t)pid * TSPLIT + ts] = (x * x + y * y + z * z) + m;
  }
}

__global__ __launch_bounds__(256) void chamfer_reduce2_kernel(
    const float* __restrict__ wsmin, float* __restrict__ out, int npts,
    float scale) {
  int tid = blockIdx.x * blockDim.x + threadIdx.x;
  int stride = gridDim.x * blockDim.x;
  double acc = 0.0;
  for (int p = tid; p < npts; p += stride) {
    float2_t v = ((const float2_t*)wsmin)[p];
    acc += (double)fminf(v.x, v.y);
  }
  for (int off = 32; off > 0; off >>= 1) acc += __shfl_down(acc, off, 64);
  __shared__ double wsum[256 / 64];
  int t = threadIdx.x;
  if ((t & 63) == 0) wsum[t >> 6] = acc;
  __syncthreads();
  if (t == 0) {
    double s = 0.0;
#pragma unroll
    for (int w = 0; w < 256 / 64; ++w) s += wsum[w];
    atomicAdd(out, (float)(s * (double)scale));
  }
}

extern "C" void kernel_launch(void* const* d_in, const int* in_sizes, int n_in,
                              void* d_out, int out_size, void* d_ws,
                              size_t ws_size, hipStream_t stream) {
  const float* pred = (const float*)d_in[0];
  const float* target = (const float*)d_in[1];
  float* out = (float*)d_out;
  const int B = 4;
  const int M = in_sizes[0] / (B * 3);  // 8192
  float scale = 1.0f / (float)(B * M);

  hipMemsetAsync(out, 0, sizeof(float), stream);  // d_out is poisoned 0xAA

  // layout: wsmin [B*2*M f32] | sorted [B*2*M float4] | binBase | hdr
  size_t needWsmin = (size_t)B * 2 * M * 4;           // 256 KB
  size_t needSorted = (size_t)B * 2 * M * 16;         // 1 MB
  size_t needBins = (size_t)B * 2 * (NBINS + 1) * 4;  // ~8 KB
  int nslabs = B * 2 * (M / SLABP);                   // 2048
  size_t needHdr = (size_t)nslabs * 4 * 4;            // 32 KB
  size_t need = needWsmin + needSorted + needBins + needHdr;

  if (ws_size >= need) {
    float* wsmin = (float*)d_ws;
    float4_t* sorted = (float4_t*)((char*)d_ws + needWsmin);
    int* binBase = (int*)((char*)sorted + needSorted);
    int* hdr = (int*)((char*)binBase + needBins);

    bin_sort_kernel<<<B * 2, BST, 0, stream>>>(pred, target, sorted, binBase,
                                               M);
    bound_kernel<<<nslabs / 2, 64, 0, stream>>>(sorted, binBase, hdr, M);
    slab_kernel<<<nslabs, 256, 0, stream>>>(sorted, hdr, wsmin, M);
    int npts = B * 2 * M;  // 65536
    chamfer_reduce_kernel<<<64, 256, 0, stream>>>(wsmin, out, npts, scale);
  } else {
    // fallback: R11 brute force, 512 KB ws (known-good at 46.4us dispatch)
    float* wsmin = (float*)d_ws;
    int blocks = B * 2 * (M / G) * TSPLIT;  // 1024
    chamfer_brute_kernel<<<blocks, THREADS, 0, stream>>>(pred, target, wsmin,
                                                         M);
    int npts = B * 2 * M;
    chamfer_reduce2_kernel<<<64, 256, 0, stream>>>(wsmin, out, npts, scale);
  }
}